// Round 14
// baseline (200.321 us; speedup 1.0000x reference)
//
#include <hip/hip_runtime.h>

#define N_NODES 50000
#define D_NB 16
#define IN_DIM 256
#define OUT_DIM 128
#define K_HEADS 4
#define SLOPE 0.01f
#define NSLICE 16       // slice s = k*4 + cb; 32 cols each
#define SLICE_COLS 32
#define CHUNK 256       // nodes per block-level steal
#define NCHUNKS ((N_NODES + CHUNK - 1) / CHUNK)   // 196

typedef __attribute__((ext_vector_type(8))) short short8;
typedef __attribute__((ext_vector_type(4))) float f32x4;
typedef __attribute__((ext_vector_type(2))) float f32x2;

static __device__ __forceinline__ unsigned short f2bf(float f) {
    unsigned u = __float_as_uint(f);
    unsigned r = u + 0x7fffu + ((u >> 16) & 1u);   // RNE
    return (unsigned short)(r >> 16);
}
static __device__ __forceinline__ float bf2f(unsigned short b) {
    return __uint_as_float(((unsigned)b) << 16);
}

// ---------------- Kernel 0: W (f32) -> Wb (bf16), same [K][OUT][IN] layout ----------------
__global__ void wb_kernel(const float* __restrict__ W, unsigned short* __restrict__ Wb) {
    int id = blockIdx.x * blockDim.x + threadIdx.x;
    if (id < K_HEADS * OUT_DIM * IN_DIM) Wb[id] = f2bf(W[id]);
}

// ---------------- Kernel 1: MFMA GEMM (unchanged; e layout [k][N]) ----------------
__global__ __launch_bounds__(256) void gemm_kernel(
    const float* __restrict__ X, const unsigned short* __restrict__ Wb,
    const float* __restrict__ a,
    unsigned short* __restrict__ Whb2, float* __restrict__ e_nb, float* __restrict__ e_self)
{
    __shared__ unsigned short Wlds[2][SLICE_COLS * IN_DIM];   // 2 x 16 KB

    const int t = threadIdx.x;
    const int lane = t & 63;
    const int w = t >> 6;
    const int lrow = lane & 15;
    const int lk = lane >> 4;
    const int m0 = blockIdx.x * 64 + w * 16;

    const int arow = m0 + lrow;
    const bool avalid = arow < N_NODES;

    const float* Xr = X + (size_t)arow * IN_DIM + lk * 8;
    short8 af[8];
    #pragma unroll
    for (int kk = 0; kk < 8; ++kk) {
        short8 s;
        if (avalid) {
            float4 x0 = *(const float4*)(Xr + kk * 32);
            float4 x1 = *(const float4*)(Xr + kk * 32 + 4);
            s[0] = (short)f2bf(x0.x); s[1] = (short)f2bf(x0.y);
            s[2] = (short)f2bf(x0.z); s[3] = (short)f2bf(x0.w);
            s[4] = (short)f2bf(x1.x); s[5] = (short)f2bf(x1.y);
            s[6] = (short)f2bf(x1.z); s[7] = (short)f2bf(x1.w);
        } else {
            s = short8{0, 0, 0, 0, 0, 0, 0, 0};
        }
        af[kk] = s;
    }

    auto STAGE = [&](int st, int buf) {
        const unsigned short* WbS = Wb + (size_t)st * SLICE_COLS * IN_DIM;
        #pragma unroll
        for (int i = 0; i < 4; ++i) {
            const int c = i * 256 + t;
            const int r = c >> 5;
            const int p = c & 31;
            const int cu = p ^ (r & 7);
            const unsigned short* gsrc = WbS + r * IN_DIM + cu * 8;
            unsigned short* ldst = &Wlds[buf][c * 8];
            __builtin_amdgcn_global_load_lds(
                (const __attribute__((address_space(1))) void*)gsrc,
                (__attribute__((address_space(3))) void*)ldst, 16, 0, 0);
        }
    };

    float pnb = 0.f, psf = 0.f;
    STAGE(0, 0);
    __syncthreads();

    for (int st = 0; st < NSLICE; ++st) {
        const int buf = st & 1;
        if (st + 1 < NSLICE) STAGE(st + 1, buf ^ 1);

        f32x4 acc[2] = {};
        #pragma unroll
        for (int kk = 0; kk < 8; ++kk) {
            #pragma unroll
            for (int nt = 0; nt < 2; ++nt) {
                const int row = nt * 16 + lrow;
                const int pos = (kk * 4 + lk) ^ (row & 7);
                const short8 bf = *(const short8*)(&Wlds[buf][row * IN_DIM + pos * 8]);
                acc[nt] = __builtin_amdgcn_mfma_f32_16x16x32_bf16(bf, af[kk], acc[nt], 0, 0, 0);
            }
        }

        const int k = st >> 2, cb = st & 3;
        #pragma unroll
        for (int nt = 0; nt < 2; ++nt) {
            const float4 anb = *(const float4*)(a + k * 2 * OUT_DIM + cb * 32 + nt * 16 + lk * 4);
            const float4 asf = *(const float4*)(a + k * 2 * OUT_DIM + OUT_DIM + cb * 32 + nt * 16 + lk * 4);
            pnb += acc[nt][0] * anb.x + acc[nt][1] * anb.y
                 + acc[nt][2] * anb.z + acc[nt][3] * anb.w;
            psf += acc[nt][0] * asf.x + acc[nt][1] * asf.y
                 + acc[nt][2] * asf.z + acc[nt][3] * asf.w;
            if (avalid) {
                uint2 pk;
                pk.x = (unsigned)f2bf(acc[nt][0]) | ((unsigned)f2bf(acc[nt][1]) << 16);
                pk.y = (unsigned)f2bf(acc[nt][2]) | ((unsigned)f2bf(acc[nt][3]) << 16);
                *(uint2*)(Whb2 + ((size_t)st * N_NODES + arow) * SLICE_COLS + nt * 16 + lk * 4) = pk;
            }
        }
        if ((st & 3) == 3) {
            pnb += __shfl_xor(pnb, 16); pnb += __shfl_xor(pnb, 32);
            psf += __shfl_xor(psf, 16); psf += __shfl_xor(psf, 32);
            if (avalid && lane < 16) {
                e_nb[(size_t)k * N_NODES + arow] = pnb;     // [k][N] layout
                e_self[(size_t)k * N_NODES + arow] = psf;
            }
            pnb = 0.f; psf = 0.f;
        }
        __syncthreads();
    }
}

// ---------------- Kernel 2a: softmax -> alpha[k][n][16] f32 (once per node,head) ----------------
__global__ __launch_bounds__(256) void alpha_kernel(
    const int* __restrict__ nidx, const float* __restrict__ e_nb,
    const float* __restrict__ e_self, float* __restrict__ alpha)
{
    const int t = threadIdx.x;
    const int w = t >> 6;
    const int lane = t & 63;
    const int nl = lane >> 4;
    const int d = lane & 15;
    const int n = (blockIdx.x * 4 + w) * 4 + nl;

    const int nbr = __builtin_nontemporal_load(nidx + (size_t)n * D_NB + d);
    #pragma unroll
    for (int k = 0; k < K_HEADS; ++k) {
        const float es = e_self[(size_t)k * N_NODES + n];
        const float x = e_nb[(size_t)k * N_NODES + nbr] + es;
        const float v = x > 0.f ? x : SLOPE * x;
        float m = v;
        #pragma unroll
        for (int sh = 8; sh >= 1; sh >>= 1) m = fmaxf(m, __shfl_xor(m, sh, 16));
        const float pz = __expf(v - m);
        float sum = pz;
        #pragma unroll
        for (int sh = 8; sh >= 1; sh >>= 1) sum += __shfl_xor(sum, sh, 16);
        __builtin_nontemporal_store(pz / sum,
            alpha + ((size_t)k * N_NODES + n) * D_NB + d);
    }
}

// ---------------- Kernel 2b: XCC-sliced gather, 16B/lane, 8-deep batched loads ----------------
// Blocks on XCD x (via HW_REG_XCC_ID) steal 256-node chunks of slice x then x+8.
// 4 lanes per node (16 nodes/wave): lanes c=0..3 read cols c*8..c*8+7 (uint4 = 16B);
// one gather instruction fetches 16 random 64B rows. dd-loop in 2 batches of 8
// statically-indexed uint4 loads -> 8 outstanding instrs x 16 lines = 128 lines in flight.
__global__ __launch_bounds__(256) void gather_kernel(
    const int* __restrict__ nidx, const unsigned short* __restrict__ Whb2,
    const float* __restrict__ alpha, float* __restrict__ out, int* __restrict__ ctr)
{
    unsigned xcc;
    asm volatile("s_getreg_b32 %0, hwreg(HW_REG_XCC_ID)" : "=s"(xcc));
    xcc &= 7;

    __shared__ int c_sh;
    const int t = threadIdx.x;
    const int w = t >> 6;
    const int lane = t & 63;
    const int g = lane >> 2;                // node subgroup (0..15)
    const int c = lane & 3;                 // col-octet (8 cols = 16 B)

    while (true) {
        __syncthreads();
        if (t == 0) c_sh = atomicAdd(&ctr[xcc * 32], 1);
        __syncthreads();
        const int ch = c_sh;
        if (ch >= 2 * NCHUNKS) break;

        const int s = (int)xcc + (ch >= NCHUNKS ? 8 : 0);
        const int k = s >> 2;               // head
        const int cb = s & 3;               // col-block
        const int base = (ch >= NCHUNKS ? ch - NCHUNKS : ch) * CHUNK + w * (CHUNK / 4);
        const unsigned short* S = Whb2 + (size_t)s * N_NODES * SLICE_COLS;
        const float* A = alpha + (size_t)k * N_NODES * D_NB;

        #pragma unroll
        for (int j = 0; j < 4; ++j) {            // 4 j-iters x 16 nodes/wave
            const int n = base + j * 16 + g;
            const bool nv = n < N_NODES;

            int nbrq[4]; float alq[4];
            #pragma unroll
            for (int q = 0; q < 4; ++q) {        // lane c holds dd = q*4 + c
                nbrq[q] = nv ? __builtin_nontemporal_load(nidx + (size_t)n * D_NB + q * 4 + c) : 0;
                alq[q]  = nv ? __builtin_nontemporal_load(A + (size_t)n * D_NB + q * 4 + c) : 0.f;
            }

            float acc[8] = {};
            #pragma unroll
            for (int h = 0; h < 2; ++h) {
                uint4 u[8]; float ad[8];
                #pragma unroll
                for (int b = 0; b < 8; ++b) {
                    const int dd = h * 8 + b;
                    const int src = (lane & 0x3C) | (dd & 3);
                    const int   nd = __shfl(nbrq[dd >> 2], src);
                    ad[b] = __shfl(alq[dd >> 2], src);
                    u[b] = *(const uint4*)(S + (size_t)nd * SLICE_COLS + c * 8);
                }
                #pragma unroll
                for (int b = 0; b < 8; ++b) {
                    acc[0] += ad[b] * bf2f((unsigned short)(u[b].x & 0xffffu));
                    acc[1] += ad[b] * bf2f((unsigned short)(u[b].x >> 16));
                    acc[2] += ad[b] * bf2f((unsigned short)(u[b].y & 0xffffu));
                    acc[3] += ad[b] * bf2f((unsigned short)(u[b].y >> 16));
                    acc[4] += ad[b] * bf2f((unsigned short)(u[b].z & 0xffffu));
                    acc[5] += ad[b] * bf2f((unsigned short)(u[b].z >> 16));
                    acc[6] += ad[b] * bf2f((unsigned short)(u[b].w & 0xffffu));
                    acc[7] += ad[b] * bf2f((unsigned short)(u[b].w >> 16));
                }
            }
            if (nv) {
                float* op = out + (size_t)n * (K_HEADS * OUT_DIM) + k * OUT_DIM
                            + cb * SLICE_COLS + c * 8;
                __builtin_nontemporal_store(f32x4{acc[0], acc[1], acc[2], acc[3]}, (f32x4*)op);
                __builtin_nontemporal_store(f32x4{acc[4], acc[5], acc[6], acc[7]}, (f32x4*)(op + 4));
            }
        }
    }
}

// ---------------- launch ----------------
extern "C" void kernel_launch(void* const* d_in, const int* in_sizes, int n_in,
                              void* d_out, int out_size, void* d_ws, size_t ws_size,
                              hipStream_t stream) {
    const float* X = (const float*)d_in[0];
    const float* W = (const float*)d_in[1];
    const float* a = (const float*)d_in[2];
    const int* nidx = (const int*)d_in[3];
    float* out = (float*)d_out;

    char* p = (char*)d_ws;
    unsigned short* Wb = (unsigned short*)p;      p += (size_t)K_HEADS * OUT_DIM * IN_DIM * 2;
    unsigned short* Whb2 = (unsigned short*)p;    p += (size_t)NSLICE * N_NODES * SLICE_COLS * 2;
    float* enb = (float*)p;                       p += (size_t)N_NODES * K_HEADS * 4;
    float* eself = (float*)p;                     p += (size_t)N_NODES * K_HEADS * 4;
    float* alpha = (float*)p;                     p += (size_t)K_HEADS * N_NODES * D_NB * 4;
    int* ctr = (int*)p;                           // 8 counters, 128B apart

    hipLaunchKernelGGL(wb_kernel,
        dim3((K_HEADS * OUT_DIM * IN_DIM + 255) / 256), dim3(256), 0, stream, W, Wb);

    hipLaunchKernelGGL(gemm_kernel,
        dim3((N_NODES + 63) / 64), dim3(256), 0, stream, X, Wb, a, Whb2, enb, eself);

    hipMemsetAsync(ctr, 0, 8 * 32 * sizeof(int), stream);

    hipLaunchKernelGGL(alpha_kernel,
        dim3(N_NODES / 16), dim3(256), 0, stream, nidx, enb, eself, alpha);

    hipLaunchKernelGGL(gather_kernel,
        dim3(2048), dim3(256), 0, stream, nidx, Whb2, alpha, out, ctr);
}

// Round 15
// 177.060 us; speedup vs baseline: 1.1314x; 1.1314x over previous
//
#include <hip/hip_runtime.h>

#define N_NODES 50000
#define D_NB 16
#define IN_DIM 256
#define OUT_DIM 128
#define K_HEADS 4
#define SLOPE 0.01f
#define NSLICE 16       // GEMM2 stage s = k*4 + cb; 32 out-cols each
#define SLICE_COLS 32

typedef __attribute__((ext_vector_type(8))) short short8;
typedef __attribute__((ext_vector_type(4))) float f32x4;

static __device__ __forceinline__ unsigned f2bf(float f) {
    unsigned u = __float_as_uint(f);
    unsigned r = u + 0x7fffu + ((u >> 16) & 1u);   // RNE
    return r >> 16;
}
static __device__ __forceinline__ float bf2f(unsigned short b) {
    return __uint_as_float(((unsigned)b) << 16);
}

// ---------------- Kernel 0: W (f32) -> Wb (bf16), same [K][OUT][IN] layout ----------------
__global__ void wb_kernel(const float* __restrict__ W, unsigned short* __restrict__ Wb) {
    int id = blockIdx.x * blockDim.x + threadIdx.x;
    if (id < K_HEADS * OUT_DIM * IN_DIM) Wb[id] = (unsigned short)f2bf(W[id]);
}

// ---------------- Kernel 1: wt8[v][i] = sum_o W[k][o][i] * a[k][s*128+o],  v = k*2+s ----------
__global__ __launch_bounds__(256) void wt8_kernel(
    const float* __restrict__ W, const float* __restrict__ a, float* __restrict__ wt8)
{
    const int i = threadIdx.x;      // 0..255
    #pragma unroll
    for (int k = 0; k < K_HEADS; ++k) {
        float s0 = 0.f, s1 = 0.f;
        for (int o = 0; o < OUT_DIM; ++o) {
            const float w = W[((size_t)k * OUT_DIM + o) * IN_DIM + i];
            s0 += w * a[k * 2 * OUT_DIM + o];
            s1 += w * a[k * 2 * OUT_DIM + OUT_DIM + o];
        }
        wt8[(k * 2 + 0) * IN_DIM + i] = s0;
        wt8[(k * 2 + 1) * IN_DIM + i] = s1;
    }
}

// ---------------- Kernel 2: prep — Xb = bf16(X); e_nb/e_self[k][n] = X[n]·wt8 (f32) ----------
// Wave = 1 node. Lane l holds X components 4l..4l+3.
__global__ __launch_bounds__(256) void prep_kernel(
    const float* __restrict__ X, const float* __restrict__ wt8,
    unsigned short* __restrict__ Xb, float* __restrict__ e_nb, float* __restrict__ e_self)
{
    const int t = threadIdx.x;
    const int w = t >> 6;
    const int lane = t & 63;
    const int n = blockIdx.x * 4 + w;

    const float4 x = *(const float4*)(X + (size_t)n * IN_DIM + lane * 4);
    uint2 pk;
    pk.x = f2bf(x.x) | (f2bf(x.y) << 16);
    pk.y = f2bf(x.z) | (f2bf(x.w) << 16);
    *(uint2*)(Xb + (size_t)n * IN_DIM + lane * 4) = pk;

    float p[8];
    #pragma unroll
    for (int v = 0; v < 8; ++v) {
        const float4 wv = *(const float4*)(wt8 + v * IN_DIM + lane * 4);
        p[v] = x.x * wv.x + x.y * wv.y + x.z * wv.z + x.w * wv.w;
    }
    #pragma unroll
    for (int sh = 32; sh >= 1; sh >>= 1) {
        #pragma unroll
        for (int v = 0; v < 8; ++v) p[v] += __shfl_xor(p[v], sh);
    }
    if (lane < 8) {
        const int k = lane >> 1;
        float* dst = (lane & 1) ? e_self : e_nb;
        dst[(size_t)k * N_NODES + n] = p[lane];
    }
}

// ---------------- Kernel 3: fused alpha + X-gather aggregation ----------------
// Wave = 1 node. Lane l: head k=l>>4, slot dl=l&15 for the softmax; whole wave gathers
// Xb[nbr] rows (8 B/lane, 512 B contiguous per instruction) and accumulates all 4 heads.
// Output aggX[k][n-n0][256] bf16.
__global__ __launch_bounds__(256) void agg_kernel(
    const int* __restrict__ nidx, const unsigned short* __restrict__ Xb,
    const float* __restrict__ e_nb, const float* __restrict__ e_self,
    unsigned short* __restrict__ aggX, int n0, int nc)
{
    const int t = threadIdx.x;
    const int w = t >> 6;
    const int lane = t & 63;
    const int n = n0 + blockIdx.x * 4 + w;
    if (n >= n0 + nc || n >= N_NODES) return;

    const int k = lane >> 4;
    const int dl = lane & 15;

    const int nbr = nidx[(size_t)n * D_NB + dl];
    const float x = e_nb[(size_t)k * N_NODES + nbr] + e_self[(size_t)k * N_NODES + n];
    const float v = x > 0.f ? x : SLOPE * x;
    float m = v;
    #pragma unroll
    for (int sh = 8; sh >= 1; sh >>= 1) m = fmaxf(m, __shfl_xor(m, sh, 16));
    const float pz = __expf(v - m);
    float sum = pz;
    #pragma unroll
    for (int sh = 8; sh >= 1; sh >>= 1) sum += __shfl_xor(sum, sh, 16);
    const float alpha = pz / sum;

    float acc[4][4] = {};
    #pragma unroll
    for (int h = 0; h < 2; ++h) {
        uint2 u[8];
        #pragma unroll
        for (int b = 0; b < 8; ++b) {
            const int nd = __shfl(nbr, h * 8 + b);
            u[b] = *(const uint2*)(Xb + (size_t)nd * IN_DIM + lane * 4);
        }
        #pragma unroll
        for (int b = 0; b < 8; ++b) {
            const float x0 = bf2f((unsigned short)(u[b].x & 0xffffu));
            const float x1 = bf2f((unsigned short)(u[b].x >> 16));
            const float x2 = bf2f((unsigned short)(u[b].y & 0xffffu));
            const float x3 = bf2f((unsigned short)(u[b].y >> 16));
            #pragma unroll
            for (int kk = 0; kk < 4; ++kk) {
                const float ad = __shfl(alpha, kk * 16 + h * 8 + b);
                acc[kk][0] += ad * x0;
                acc[kk][1] += ad * x1;
                acc[kk][2] += ad * x2;
                acc[kk][3] += ad * x3;
            }
        }
    }
    #pragma unroll
    for (int kk = 0; kk < 4; ++kk) {
        uint2 pk;
        pk.x = f2bf(acc[kk][0]) | (f2bf(acc[kk][1]) << 16);
        pk.y = f2bf(acc[kk][2]) | (f2bf(acc[kk][3]) << 16);
        *(uint2*)(aggX + ((size_t)kk * nc + (n - n0)) * IN_DIM + lane * 4) = pk;
    }
}

// ---------------- Kernel 4: GEMM2 — out[n][k*128+o] = aggX[k][n]·W[k][o] (MFMA) ----------------
// Same staged structure as the proven GEMM1: 16 stages (k,cb), 32 out-cols staged to 16KB
// LDS double-buffer via global_load_lds (pre-swizzled source); A-frags reloaded per head
// directly from aggX (bf16, 16B loads). Operand-swapped MFMA -> 16B f32 output stores.
__global__ __launch_bounds__(256) void gemm2_kernel(
    const unsigned short* __restrict__ aggX, const unsigned short* __restrict__ Wb,
    float* __restrict__ out, int n0, int nc)
{
    __shared__ unsigned short Wlds[2][SLICE_COLS * IN_DIM];   // 2 x 16 KB

    const int t = threadIdx.x;
    const int lane = t & 63;
    const int w = t >> 6;
    const int lrow = lane & 15;
    const int lk = lane >> 4;
    const int m0 = n0 + blockIdx.x * 64 + w * 16;

    const int arow = m0 + lrow;
    const bool avalid = (arow < n0 + nc) && (arow < N_NODES);

    auto STAGE = [&](int st, int buf) {
        const unsigned short* WbS = Wb + (size_t)st * SLICE_COLS * IN_DIM;
        #pragma unroll
        for (int i = 0; i < 4; ++i) {
            const int c = i * 256 + t;
            const int r = c >> 5;
            const int p = c & 31;
            const int cu = p ^ (r & 7);
            const unsigned short* gsrc = WbS + r * IN_DIM + cu * 8;
            unsigned short* ldst = &Wlds[buf][c * 8];
            __builtin_amdgcn_global_load_lds(
                (const __attribute__((address_space(1))) void*)gsrc,
                (__attribute__((address_space(3))) void*)ldst, 16, 0, 0);
        }
    };

    short8 af[8];
    STAGE(0, 0);
    __syncthreads();

    for (int st = 0; st < NSLICE; ++st) {
        const int buf = st & 1;
        if (st + 1 < NSLICE) STAGE(st + 1, buf ^ 1);

        if ((st & 3) == 0) {   // new head: reload A fragments from aggX
            const unsigned short* Ar = aggX
                + ((size_t)(st >> 2) * nc + (arow - n0)) * IN_DIM + lk * 8;
            #pragma unroll
            for (int kk = 0; kk < 8; ++kk)
                af[kk] = avalid ? *(const short8*)(Ar + kk * 32)
                                : short8{0, 0, 0, 0, 0, 0, 0, 0};
        }

        f32x4 acc[2] = {};
        #pragma unroll
        for (int kk = 0; kk < 8; ++kk) {
            #pragma unroll
            for (int nt = 0; nt < 2; ++nt) {
                const int row = nt * 16 + lrow;
                const int pos = (kk * 4 + lk) ^ (row & 7);
                const short8 bf = *(const short8*)(&Wlds[buf][row * IN_DIM + pos * 8]);
                acc[nt] = __builtin_amdgcn_mfma_f32_16x16x32_bf16(bf, af[kk], acc[nt], 0, 0, 0);
            }
        }

        const int k = st >> 2, cb = st & 3;
        if (avalid) {
            #pragma unroll
            for (int nt = 0; nt < 2; ++nt) {
                *(f32x4*)(out + (size_t)arow * (K_HEADS * OUT_DIM)
                          + k * OUT_DIM + cb * SLICE_COLS + nt * 16 + lk * 4) = acc[nt];
            }
        }
        __syncthreads();
    }
}

// ---------------- launch ----------------
extern "C" void kernel_launch(void* const* d_in, const int* in_sizes, int n_in,
                              void* d_out, int out_size, void* d_ws, size_t ws_size,
                              hipStream_t stream) {
    const float* X = (const float*)d_in[0];
    const float* W = (const float*)d_in[1];
    const float* a = (const float*)d_in[2];
    const int* nidx = (const int*)d_in[3];
    float* out = (float*)d_out;

    const size_t WbB  = (size_t)K_HEADS * OUT_DIM * IN_DIM * 2;
    const size_t XbB  = (size_t)N_NODES * IN_DIM * 2;
    const size_t wt8B = (size_t)8 * IN_DIM * 4;
    const size_t eB   = (size_t)K_HEADS * N_NODES * 4;
    auto need = [&](int nc) {
        return WbB + XbB + wt8B + 2 * eB + (size_t)K_HEADS * nc * IN_DIM * 2 + 1024;
    };

    int np, nc;
    if      (ws_size >= need(50000)) { np = 1; nc = 50000; }
    else if (ws_size >= need(25000)) { np = 2; nc = 25000; }
    else                             { np = 4; nc = 12500; }

    char* p = (char*)d_ws;
    unsigned short* Wb   = (unsigned short*)p;   p += WbB;
    unsigned short* Xb   = (unsigned short*)p;   p += XbB;
    float*          wt8  = (float*)p;            p += wt8B;
    float*          enb  = (float*)p;            p += eB;
    float*          esf  = (float*)p;            p += eB;
    unsigned short* aggX = (unsigned short*)p;

    hipLaunchKernelGGL(wb_kernel,
        dim3((K_HEADS * OUT_DIM * IN_DIM + 255) / 256), dim3(256), 0, stream, W, Wb);

    hipLaunchKernelGGL(wt8_kernel, dim3(1), dim3(256), 0, stream, W, a, wt8);

    hipLaunchKernelGGL(prep_kernel,
        dim3(N_NODES / 4), dim3(256), 0, stream, X, wt8, Xb, enb, esf);

    for (int pass = 0; pass < np; ++pass) {
        const int nb0 = pass * nc;
        hipLaunchKernelGGL(agg_kernel,
            dim3((nc + 3) / 4), dim3(256), 0, stream, nidx, Xb, enb, esf, aggX, nb0, nc);
        hipLaunchKernelGGL(gemm2_kernel,
            dim3((nc + 63) / 64), dim3(256), 0, stream, aggX, Wb, out, nb0, nc);
    }
}